// Round 16
// baseline (177.372 us; speedup 1.0000x reference)
//
#include <hip/hip_runtime.h>
#include <hip/hip_bf16.h>

typedef short short4v __attribute__((ext_vector_type(4)));
typedef short short8 __attribute__((ext_vector_type(8)));
typedef float float4v __attribute__((ext_vector_type(4)));

#define HEADS 16
#define HDIM 64
#define TOKDIM 1024
#define SEQ 2048
#define BATCH 2
#define BH (BATCH*HEADS)
#define MROWS (BATCH*SEQ)

__device__ __forceinline__ short f2b(float f) {
    __hip_bfloat16 h = __float2bfloat16(f);
    return *reinterpret_cast<short*>(&h);
}
__device__ __forceinline__ float b2f(short s) {
    __hip_bfloat16 h;
    *reinterpret_cast<short*>(&h) = s;
    return __bfloat162float(h);
}
__device__ __forceinline__ short8 load8_f32_bf16(const float* __restrict__ p) {
    float4v a = *(const float4v*)p;
    float4v b = *(const float4v*)(p + 4);
    short8 r;
    r[0]=f2b(a[0]); r[1]=f2b(a[1]); r[2]=f2b(a[2]); r[3]=f2b(a[3]);
    r[4]=f2b(b[0]); r[5]=f2b(b[1]); r[6]=f2b(b[2]); r[7]=f2b(b[3]);
    return r;
}
// fast pack: RN each fp32 to bf16 (bits+0x8000), byte-pack highs via v_perm
__device__ __forceinline__ int packrn(float a, float b) {
    unsigned ua = __float_as_uint(a) + 0x8000u;
    unsigned ub = __float_as_uint(b) + 0x8000u;
    return (int)__builtin_amdgcn_perm(ub, ua, 0x07060302u);
}
// hardware exp2 (avoid glibc __exp2f macro collision)
__device__ __forceinline__ float hexp2(float x) {
    return __builtin_amdgcn_exp2f(x);
}

// async global->LDS DMA, 16B/lane; LDS dest = wave-uniform base + lane*16
__device__ __forceinline__ void stage16(const void* g, void* l) {
    __builtin_amdgcn_global_load_lds((const __attribute__((address_space(1))) void*)g,
                                     (__attribute__((address_space(3))) void*)l, 16, 0, 0);
}

// ---------------------------------------------------------------------------
// One-time fp32 -> bf16 conversion for x (optional), wqkv, wout.
// ---------------------------------------------------------------------------
__global__ __launch_bounds__(256)
void cvt_bf16(const float* __restrict__ x,  short* __restrict__ xb,  int n8x,
              const float* __restrict__ wq, short* __restrict__ wqb, int n8q,
              const float* __restrict__ wo, short* __restrict__ wob, int n8o)
{
    int i = blockIdx.x*256 + threadIdx.x;
    const float* s; short* d; int off;
    if (i < n8x)                  { s = x;  d = xb;  off = i; }
    else if (i < n8x + n8q)       { s = wq; d = wqb; off = i - n8x; }
    else if (i < n8x + n8q + n8o) { s = wo; d = wob; off = i - n8x - n8q; }
    else return;
    *(short8*)&d[(size_t)off*8] = load8_f32_bf16(&s[(size_t)off*8]);
}

// ---------------------------------------------------------------------------
// QKV GEMM, m97-style staging (round-0 form) + XCD-chunked swizzle (round-16:
// grid 768 %8==0 -> bijective; each XCD gets 96 consecutive logical blocks =
// 3 m-rows x 3 W-panels, so each 0.25 MB W-panel is served from ONE XCD's L2
// to its 32 consumer blocks — validated mechanism from attn round-15 where
// the same remap cut FETCH 69.7 -> 12.4 MB).
// ---------------------------------------------------------------------------
template<int ABF16>
__global__ __launch_bounds__(256)
void gemm_qkv(const void* __restrict__ Ap, const short* __restrict__ Wq,
              short* __restrict__ Qo, short* __restrict__ Ko, short* __restrict__ Vto)
{
    __shared__ __align__(16) short As[128*32];
    __shared__ __align__(16) short Bs[128*32];
    const int tid  = threadIdx.x;
    const int lane = tid & 63;
    const int wave = tid >> 6;
    const int wm = wave >> 1, wn = wave & 1;

    // XCD-chunked bijective swizzle: grid (32,24) = 768 blocks, 768/8 = 96.
    const int lin  = blockIdx.x + gridDim.x * blockIdx.y;
    const int wgid = (lin & 7) * 96 + (lin >> 3);
    const int m0 = (wgid & 31) * 128;          // gridDim.x == 32
    const int n0 = (wgid >> 5) * 128;

    const int col16 = lane & 15, quad = lane >> 4;
    const int srow = lane >> 2;
    const int scol = (lane & 3) * 8;

    float4v acc[4][4];
    #pragma unroll
    for (int i=0;i<4;i++)
        #pragma unroll
        for (int j=0;j<4;j++) acc[i][j] = (float4v){0.f,0.f,0.f,0.f};

    for (int k0 = 0; k0 < TOKDIM; k0 += 32) {
        __syncthreads();
        if (ABF16) {
            const short* A = (const short*)Ap;
            #pragma unroll
            for (int j=0;j<2;++j) {
                const int rb = (wave*2 + j) * 16;
                stage16(&A[(size_t)(m0 + rb + srow)*TOKDIM + k0 + scol], &As[rb*32]);
            }
        } else {
            const float* A = (const float*)Ap;
            #pragma unroll
            for (int s=0;s<2;++s) {
                int blk = tid + s*256;
                int r = blk >> 2, kb = blk & 3;
                *(short8*)&As[r*32 + kb*8] = load8_f32_bf16(&A[(size_t)(m0+r)*TOKDIM + k0 + kb*8]);
            }
        }
        #pragma unroll
        for (int j=0;j<2;++j) {
            const int rb = (wave*2 + j) * 16;
            stage16(&Wq[(size_t)(n0 + rb + srow)*TOKDIM + k0 + scol], &Bs[rb*32]);
        }
        __syncthreads();

        short8 af[4], bfr[4];
        #pragma unroll
        for (int i=0;i<4;i++) af[i]  = *(const short8*)&As[(wm*64 + i*16 + col16)*32 + quad*8];
        #pragma unroll
        for (int j=0;j<4;j++) bfr[j] = *(const short8*)&Bs[(wn*64 + j*16 + col16)*32 + quad*8];
        #pragma unroll
        for (int i=0;i<4;i++)
            #pragma unroll
            for (int j=0;j<4;j++)
                acc[i][j] = __builtin_amdgcn_mfma_f32_16x16x32_bf16(af[i], bfr[j], acc[i][j], 0,0,0);
    }

    #pragma unroll
    for (int i=0;i<4;i++)
        #pragma unroll
        for (int j=0;j<4;j++) {
            const int n = n0 + wn*64 + j*16 + col16;
            const int part = n >> 10;         // 0=Q 1=K 2=V
            const int h = (n & 1023) >> 6;
            const int d = n & 63;
            const int mb = m0 + wm*64 + i*16 + quad*4;
            const int b = mb >> 11;
            const int t = mb & 2047;
            if (part == 2) {
                union { short4v s; int2 i2; } w;
                #pragma unroll
                for (int r=0;r<4;r++) w.s[r] = f2b(acc[i][j][r]);
                *(int2*)&Vto[((size_t)(b*HEADS + h)*HDIM + d)*SEQ + t] = w.i2;
            } else {
                short* dst = (part == 0) ? Qo : Ko;
                #pragma unroll
                for (int r=0;r<4;r++)
                    dst[((size_t)(b*HEADS + h)*SEQ + t + r)*HDIM + d] = f2b(acc[i][j][r]);
            }
        }
}

// ---------------------------------------------------------------------------
// Out GEMM v2 (round-12 verified) + XCD-chunked swizzle (round-16: grid 512
// %8==0; each XCD gets 64 consecutive logical blocks = one full m-column
// sharing a single 0.25 MB W-panel in its L2).
// ---------------------------------------------------------------------------
#define OBM 64
#define OBN 128
#define OBK 64
#define OKT (TOKDIM/OBK)   // 16 K-tiles

__global__ __launch_bounds__(256)
void gemm_out(const short* __restrict__ A, const short* __restrict__ W,
              const float* __restrict__ bias, float* __restrict__ C)
{
    __shared__ __align__(16) short Asl[2*OBM*OBK];   // 16 KB
    __shared__ __align__(16) short Bsl[2*OBN*OBK];   // 32 KB
    const int tid  = threadIdx.x;
    const int lane = tid & 63;
    const int wave = tid >> 6;
    const int wm = wave >> 1, wn = wave & 1;

    // XCD-chunked bijective swizzle: grid (64,8) = 512 blocks, 512/8 = 64.
    const int lin  = blockIdx.x + gridDim.x * blockIdx.y;
    const int wgid = (lin & 7) * 64 + (lin >> 3);
    const int m0 = (wgid & 63) * OBM;          // gridDim.x == 64
    const int n0 = (wgid >> 6) * OBN;

    const int col16 = lane & 15, quad = lane >> 4;

    // staging: each stage16 covers 8 rows x 128B; lane -> row lane>>3,
    // physical chunk lane&7 holds logical chunk (lane&7)^(row&7).
    const int srow = lane >> 3;                      // 0..7
    const int scol = (((lane & 7) ^ srow) << 3);     // source col, shorts

    // read-side: logical chunk (kk*4+quad) -> physical ^ (row&7)
    const int r7 = col16 & 7;
    const int rdoff0 = ((0*4 + quad) ^ r7) << 3;
    const int rdoff1 = ((1*4 + quad) ^ r7) << 3;

    float4v acc[2][4];
    #pragma unroll
    for (int i=0;i<2;i++)
        #pragma unroll
        for (int j=0;j<4;j++) acc[i][j] = (float4v){0.f,0.f,0.f,0.f};

    // ---- prologue: stage K-tile 0 into buffer 0 ----
    #pragma unroll
    for (int c=0;c<2;++c) {
        const int rb = (wave*2 + c)*8;               // 8 groups = 64 A rows
        stage16(&A[(size_t)(m0 + rb + srow)*TOKDIM + scol], &Asl[rb*OBK]);
    }
    #pragma unroll
    for (int c=0;c<4;++c) {
        const int rb = (wave*4 + c)*8;               // 16 groups = 128 W rows
        stage16(&W[(size_t)(n0 + rb + srow)*TOKDIM + scol], &Bsl[rb*OBK]);
    }
    asm volatile("s_waitcnt vmcnt(0)" ::: "memory");
    __builtin_amdgcn_s_barrier();

    for (int kt = 0; kt < OKT; ++kt) {
        const int buf = kt & 1;
        const short* Ab = &Asl[buf*OBM*OBK];
        const short* Bb = &Bsl[buf*OBN*OBK];
        short* An = &Asl[(buf^1)*OBM*OBK];
        short* Bn = &Bsl[(buf^1)*OBN*OBK];

        // issue next K-tile's stages FIRST (latency hides under compute)
        if (kt + 1 < OKT) {
            const int k1 = (kt + 1)*OBK;
            #pragma unroll
            for (int c=0;c<2;++c) {
                const int rb = (wave*2 + c)*8;
                stage16(&A[(size_t)(m0 + rb + srow)*TOKDIM + k1 + scol], &An[rb*OBK]);
            }
            #pragma unroll
            for (int c=0;c<4;++c) {
                const int rb = (wave*4 + c)*8;
                stage16(&W[(size_t)(n0 + rb + srow)*TOKDIM + k1 + scol], &Bn[rb*OBK]);
            }
        }

        #pragma unroll
        for (int kk=0;kk<2;++kk) {
            const int rdoff = kk ? rdoff1 : rdoff0;
            short8 af[2], bfr[4];
            #pragma unroll
            for (int i=0;i<2;i++)
                af[i]  = *(const short8*)&Ab[(wm*32 + i*16 + col16)*OBK + rdoff];
            #pragma unroll
            for (int j=0;j<4;j++)
                bfr[j] = *(const short8*)&Bb[(wn*64 + j*16 + col16)*OBK + rdoff];
            __builtin_amdgcn_s_setprio(1);
            #pragma unroll
            for (int i=0;i<2;i++)
                #pragma unroll
                for (int j=0;j<4;j++)
                    acc[i][j] = __builtin_amdgcn_mfma_f32_16x16x32_bf16(af[i], bfr[j], acc[i][j], 0,0,0);
            __builtin_amdgcn_s_setprio(0);
        }

        // own kt+1 loads done; barrier aligns all waves and gates buf^1 reuse
        asm volatile("s_waitcnt vmcnt(0)" ::: "memory");
        __builtin_amdgcn_s_barrier();
    }

    #pragma unroll
    for (int i=0;i<2;i++)
        #pragma unroll
        for (int j=0;j<4;j++) {
            const int n = n0 + wn*64 + j*16 + col16;
            const float bn = bias[n];
            #pragma unroll
            for (int r=0;r<4;r++) {
                const int m = m0 + wm*32 + i*16 + quad*4 + r;
                C[(size_t)m*TOKDIM + n] = acc[i][j][r] + bn;
            }
        }
}

// ---------------------------------------------------------------------------
// Flash attention v13 (round-15 verified best: FETCH 69.7->12.4 MB via XCD
// swizzle, 0 bank conflicts, ~45 us = structural floor after 5 failed
// restructure attempts). Do not restructure.
// ---------------------------------------------------------------------------
#define AQB 128
#define KT  64
#define NTH 16             // tiles per key-half
#define KVT (KT*HDIM)      // 4096 shorts per K or V tile
#define BUF2 (2*KVT)       // 8192 shorts per buffer (K|V)

__global__ __launch_bounds__(256, 2)
void attn_kernel(const short* __restrict__ Q, const short* __restrict__ K,
                 const short* __restrict__ Vt, short* __restrict__ AO)
{
    // layout: [stream 0..1][buf 0..1][ K(64x64) | V(64x64) ]  = 65536 B
    __shared__ __align__(16) short SL[2*2*BUF2];

    const int tid   = threadIdx.x;
    const int lane  = tid & 63;
    const int wave  = tid >> 6;
    const int col16 = lane & 15, quad = lane >> 4;

    // ---- XCD-chunked bijective swizzle (grid 16 x 32 = 512, %8==0) ----
    const int lin  = blockIdx.x + gridDim.x * blockIdx.y;
    const int wgid = (lin & 7) * 64 + (lin >> 3);
    const int bx   = wgid & 15;                // gridDim.x == 16
    const int bh   = wgid >> 4;

    const int qh  = wave & 1;
    const int kh2 = wave >> 1;                 // key half == stream
    const int qb  = bx*AQB + qh*64;

    const short* Qb = Q  + (size_t)bh*SEQ*HDIM;
    const short* Kb = K  + (size_t)bh*SEQ*HDIM;
    const short* Vb = Vt + (size_t)bh*HDIM*SEQ;

    short* Sbase = &SL[kh2*2*BUF2];            // this stream's two buffers
    const int kbase = kh2 * 1024;              // first key of this stream

    // ---- staging constants ----
    const int w   = wave & 1;
    const int l3  = lane >> 3;
    const int scsw = (((lane & 7) ^ l3) << 4) >> 1;   // swizzled col, shorts
    int krow[4], vrow[4];
    #pragma unroll
    for (int c=0;c<4;++c) {
        const int s = w*32 + c*8 + l3;         // dest slot / V d-row
        krow[c] = (s&32) + ((s&12)<<1) + ((s&16)>>2) + (s&3);   // ksinv(s)
        vrow[c] = s;
    }

    // ---- read-side swizzled column offsets (shorts) ----
    const int r7 = col16 & 7;
    int scol2[2];
    #pragma unroll
    for (int j=0;j<2;++j)
        scol2[j] = ((((j<<6) | (quad<<4)) ^ (r7<<4)) >> 1);

    // Q B-frags for 4 q-groups, pre-scaled by 0.125*log2(e)
    const float qscale = 0.125f * 1.44269504088896f;
    short8 qf[4][2];
    #pragma unroll
    for (int qg=0; qg<4; ++qg)
        #pragma unroll
        for (int kk=0; kk<2; ++kk) {
            short8 raw = *(const short8*)&Qb[(size_t)(qb+qg*16+col16)*HDIM + kk*32 + quad*8];
            #pragma unroll
            for (int j=0;j<8;++j) raw[j] = f2b(b2f(raw[j]) * qscale);
            qf[qg][kk] = raw;
        }

    // all-ones bf16 A-fragment for the lsum MFMA
    const short one_bf16 = (short)0x3F80;
    const short8 vones = {one_bf16, one_bf16, one_bf16, one_bf16,
                          one_bf16, one_bf16, one_bf16, one_bf16};

    float4v o[4][4];
    float4v o1[4];
    #pragma unroll
    for (int qg=0;qg<4;qg++) {
        #pragma unroll
        for (int dt=0;dt<4;dt++) o[qg][dt] = (float4v){0.f,0.f,0.f,0.f};
        o1[qg] = (float4v){0.f,0.f,0.f,0.f};
    }

    // ---- stage tile 0 into buffer 0 (async DMA) ----
    {
        short* Kn = Sbase;
        short* Vn = Sbase + KVT;
        #pragma unroll
        for (int c=0;c<4;++c) {
            stage16(&Kb[(size_t)(kbase + krow[c])*HDIM + scsw], &Kn[w*2048 + c*512]);
            stage16(&Vb[(size_t)vrow[c]*SEQ + kbase + scsw],    &Vn[w*2048 + c*512]);
        }
    }
    __syncthreads();                           // vmcnt(0) drain + barrier

    for (int t = 0; t < NTH; ++t) {
        short* Kc = Sbase + (t & 1)*BUF2;
        short* Vc = Kc + KVT;

        // issue next tile's async stages FIRST (latency hides under compute)
        if (t + 1 < NTH) {
            const int g1 = kbase + (t+1)*KT;
            short* Kn = Sbase + ((t & 1)^1)*BUF2;
            short* Vn = Kn + KVT;
            #pragma unroll
            for (int c=0;c<4;++c) {
                stage16(&Kb[(size_t)(g1 + krow[c])*HDIM + scsw], &Kn[w*2048 + c*512]);
                stage16(&Vb[(size_t)vrow[c]*SEQ + g1 + scsw],    &Vn[w*2048 + c*512]);
            }
        }

        // ---- compute on buffer (t&1) of this stream ----
        #pragma unroll
        for (int kk = 0; kk < 2; ++kk) {
            short8 ka[2][2];
            #pragma unroll
            for (int nt=0; nt<2; ++nt)
                #pragma unroll
                for (int kh=0; kh<2; ++kh)
                    ka[nt][kh] = *(const short8*)&Kc[(kk*32 + nt*16 + col16)*64 + scol2[kh]];
            short8 va[4];
            #pragma unroll
            for (int dt=0; dt<4; ++dt)
                va[dt] = *(const short8*)&Vc[(dt*16 + col16)*64 + scol2[kk]];

            #pragma unroll
            for (int qg=0; qg<4; ++qg) {
                float4v st[2];
                __builtin_amdgcn_s_setprio(1);
                #pragma unroll
                for (int nt=0; nt<2; ++nt) {
                    float4v z = (float4v){0.f,0.f,0.f,0.f};
                    z = __builtin_amdgcn_mfma_f32_16x16x32_bf16(ka[nt][0], qf[qg][0], z, 0,0,0);
                    z = __builtin_amdgcn_mfma_f32_16x16x32_bf16(ka[nt][1], qf[qg][1], z, 0,0,0);
                    st[nt] = z;
                }
                __builtin_amdgcn_s_setprio(0);
                union { int i[4]; short8 s8; } pb;
                float p00 = hexp2(st[0][0]), p01 = hexp2(st[0][1]);
                float p02 = hexp2(st[0][2]), p03 = hexp2(st[0][3]);
                float p10 = hexp2(st[1][0]), p11 = hexp2(st[1][1]);
                float p12 = hexp2(st[1][2]), p13 = hexp2(st[1][3]);
                pb.i[0] = packrn(p00, p01); pb.i[1] = packrn(p02, p03);
                pb.i[2] = packrn(p10, p11); pb.i[3] = packrn(p12, p13);

                __builtin_amdgcn_s_setprio(1);
                #pragma unroll
                for (int dt=0; dt<4; ++dt)
                    o[qg][dt] = __builtin_amdgcn_mfma_f32_16x16x32_bf16(va[dt], pb.s8, o[qg][dt], 0,0,0);
                // row-sum of the same packed P: D[i][j] = sum_k P[k][j]
                o1[qg] = __builtin_amdgcn_mfma_f32_16x16x32_bf16(vones, pb.s8, o1[qg], 0,0,0);
                __builtin_amdgcn_s_setprio(0);
            }
        }

        __syncthreads();        // drains vmcnt (stages complete) + orders reads
    }

    // lsum: every lane of o1 holds the full key-half row sum for q = qg*16+col16
    float lsum[4];
    #pragma unroll
    for (int qg=0; qg<4; ++qg) lsum[qg] = o1[qg][0];

    // ---- merge key-halves through LDS (region: 2 qh x 64 lanes x 68 floats) ----
    float* M = (float*)SL;
    float* Mw = M + (qh*64 + lane)*68;
    if (kh2 == 1) {
        #pragma unroll
        for (int qg=0; qg<4; ++qg) {
            #pragma unroll
            for (int dt=0; dt<4; ++dt)
                *(float4v*)&Mw[(qg*4+dt)*4] = o[qg][dt];
            Mw[64+qg] = lsum[qg];
        }
    }
    __syncthreads();
    if (kh2 == 0) {
        const int b = bh >> 4, h = bh & 15;
        #pragma unroll
        for (int qg=0; qg<4; ++qg) {
            lsum[qg] += Mw[64+qg];
            const float inv = 1.0f / lsum[qg];
            const int tq = qb + qg*16 + col16;
            #pragma unroll
            for (int dt=0; dt<4; ++dt) {
                float4v ov = o[qg][dt] + *(const float4v*)&Mw[(qg*4+dt)*4];
                union { short4v s; int2 i2; } w2;
                #pragma unroll
                for (int r=0;r<4;++r) w2.s[r] = f2b(ov[r] * inv);
                *(int2*)&AO[((size_t)(b*SEQ + tq))*TOKDIM + h*64 + dt*16 + quad*4] = w2.i2;
            }
        }
    }
}

// ---------------------------------------------------------------------------
extern "C" void kernel_launch(void* const* d_in, const int* in_sizes, int n_in,
                              void* d_out, int out_size, void* d_ws, size_t ws_size,
                              hipStream_t stream)
{
    const float* x    = (const float*)d_in[0];   // [2,2048,1024] fp32
    const float* wqkv = (const float*)d_in[1];   // [3072,1024]   fp32
    const float* wout = (const float*)d_in[2];   // [1024,1024]   fp32
    const float* bout = (const float*)d_in[3];   // [1024]        fp32
    float* out = (float*)d_out;                  // [2,2048,1024] fp32

    char* ws = (char*)d_ws;
    const size_t SZ   = (size_t)BH*SEQ*HDIM*sizeof(short);     // 8 MiB
    const size_t WQB  = (size_t)3*TOKDIM*TOKDIM*sizeof(short); // 6 MiB
    const size_t WOB  = (size_t)TOKDIM*TOKDIM*sizeof(short);   // 2 MiB
    const size_t NEED_FULL = SZ + WQB + WOB + 3*SZ;            // 40 MiB
    const bool full = ws_size >= NEED_FULL;

    short *Xb, *Wqb, *Wob, *Qt, *Kt, *Vt, *AO;
    if (full) {
        Xb  = (short*)ws;
        Wqb = (short*)(ws + SZ);
        Wob = (short*)(ws + SZ + WQB);
        Qt  = (short*)(ws + SZ + WQB + WOB);
        Kt  = Qt + SZ/2;
        Vt  = Kt + SZ/2;
        AO  = Xb;
    } else {
        Xb  = nullptr;
        Wqb = (short*)ws;
        Wob = (short*)(ws + WQB);
        Qt  = (short*)(ws + WQB + WOB);
        Kt  = Qt + SZ/2;
        Vt  = Kt + SZ/2;
        AO  = Vt + SZ/2;
    }

    const int n8x = full ? (BATCH*SEQ*TOKDIM)/8 : 0;
    const int n8q = (3*TOKDIM*TOKDIM)/8;
    const int n8o = (TOKDIM*TOKDIM)/8;
    const int cvt_blocks = (n8x + n8q + n8o + 255) / 256;
    cvt_bf16<<<cvt_blocks, 256, 0, stream>>>(x, Xb, n8x, wqkv, Wqb, n8q, wout, Wob, n8o);

    if (full)
        gemm_qkv<1><<<dim3(MROWS/128, (3*TOKDIM)/128), 256, 0, stream>>>(
            (const void*)Xb, Wqb, Qt, Kt, Vt);
    else
        gemm_qkv<0><<<dim3(MROWS/128, (3*TOKDIM)/128), 256, 0, stream>>>(
            (const void*)x, Wqb, Qt, Kt, Vt);

    attn_kernel<<<dim3(SEQ/AQB, BH), 256, 0, stream>>>(Qt, Kt, Vt, AO);

    gemm_out<<<dim3(MROWS/OBM, TOKDIM/OBN), 256, 0, stream>>>(AO, Wob, bout, out);
}

// Round 17
// 168.035 us; speedup vs baseline: 1.0556x; 1.0556x over previous
//
#include <hip/hip_runtime.h>
#include <hip/hip_bf16.h>

typedef short short4v __attribute__((ext_vector_type(4)));
typedef short short8 __attribute__((ext_vector_type(8)));
typedef float float4v __attribute__((ext_vector_type(4)));

#define HEADS 16
#define HDIM 64
#define TOKDIM 1024
#define SEQ 2048
#define BATCH 2
#define BH (BATCH*HEADS)
#define MROWS (BATCH*SEQ)

__device__ __forceinline__ short f2b(float f) {
    __hip_bfloat16 h = __float2bfloat16(f);
    return *reinterpret_cast<short*>(&h);
}
__device__ __forceinline__ float b2f(short s) {
    __hip_bfloat16 h;
    *reinterpret_cast<short*>(&h) = s;
    return __bfloat162float(h);
}
__device__ __forceinline__ short8 load8_f32_bf16(const float* __restrict__ p) {
    float4v a = *(const float4v*)p;
    float4v b = *(const float4v*)(p + 4);
    short8 r;
    r[0]=f2b(a[0]); r[1]=f2b(a[1]); r[2]=f2b(a[2]); r[3]=f2b(a[3]);
    r[4]=f2b(b[0]); r[5]=f2b(b[1]); r[6]=f2b(b[2]); r[7]=f2b(b[3]);
    return r;
}
// fast pack: RN each fp32 to bf16 (bits+0x8000), byte-pack highs via v_perm
__device__ __forceinline__ int packrn(float a, float b) {
    unsigned ua = __float_as_uint(a) + 0x8000u;
    unsigned ub = __float_as_uint(b) + 0x8000u;
    return (int)__builtin_amdgcn_perm(ub, ua, 0x07060302u);
}
// hardware exp2 (avoid glibc __exp2f macro collision)
__device__ __forceinline__ float hexp2(float x) {
    return __builtin_amdgcn_exp2f(x);
}

// async global->LDS DMA, 16B/lane; LDS dest = wave-uniform base + lane*16
__device__ __forceinline__ void stage16(const void* g, void* l) {
    __builtin_amdgcn_global_load_lds((const __attribute__((address_space(1))) void*)g,
                                     (__attribute__((address_space(3))) void*)l, 16, 0, 0);
}

// ---------------------------------------------------------------------------
// One-time fp32 -> bf16 conversion for x (optional), wqkv, wout.
// ---------------------------------------------------------------------------
__global__ __launch_bounds__(256)
void cvt_bf16(const float* __restrict__ x,  short* __restrict__ xb,  int n8x,
              const float* __restrict__ wq, short* __restrict__ wqb, int n8q,
              const float* __restrict__ wo, short* __restrict__ wob, int n8o)
{
    int i = blockIdx.x*256 + threadIdx.x;
    const float* s; short* d; int off;
    if (i < n8x)                  { s = x;  d = xb;  off = i; }
    else if (i < n8x + n8q)       { s = wq; d = wqb; off = i - n8x; }
    else if (i < n8x + n8q + n8o) { s = wo; d = wob; off = i - n8x - n8q; }
    else return;
    *(short8*)&d[(size_t)off*8] = load8_f32_bf16(&s[(size_t)off*8]);
}

// ---------------------------------------------------------------------------
// QKV GEMM, m97-style staging (round-0 exact form, DEFAULT dispatch —
// round-16 proved XCD-chunked swizzle REGRESSES here: all 768 blocks are
// co-resident (3/CU), so only the XCD partition matters; default round-robin
// gives each XCD A 1MB + W 6MB = 7MB, chunked gave A 8MB + W 0.75MB = 8.75MB
// -> worse L2 fit. Keep default).
// ---------------------------------------------------------------------------
template<int ABF16>
__global__ __launch_bounds__(256)
void gemm_qkv(const void* __restrict__ Ap, const short* __restrict__ Wq,
              short* __restrict__ Qo, short* __restrict__ Ko, short* __restrict__ Vto)
{
    __shared__ __align__(16) short As[128*32];
    __shared__ __align__(16) short Bs[128*32];
    const int tid  = threadIdx.x;
    const int lane = tid & 63;
    const int wave = tid >> 6;
    const int wm = wave >> 1, wn = wave & 1;
    const int m0 = blockIdx.x * 128;
    const int n0 = blockIdx.y * 128;
    const int col16 = lane & 15, quad = lane >> 4;

    const int srow = lane >> 2;
    const int scol = (lane & 3) * 8;

    float4v acc[4][4];
    #pragma unroll
    for (int i=0;i<4;i++)
        #pragma unroll
        for (int j=0;j<4;j++) acc[i][j] = (float4v){0.f,0.f,0.f,0.f};

    for (int k0 = 0; k0 < TOKDIM; k0 += 32) {
        __syncthreads();
        if (ABF16) {
            const short* A = (const short*)Ap;
            #pragma unroll
            for (int j=0;j<2;++j) {
                const int rb = (wave*2 + j) * 16;
                stage16(&A[(size_t)(m0 + rb + srow)*TOKDIM + k0 + scol], &As[rb*32]);
            }
        } else {
            const float* A = (const float*)Ap;
            #pragma unroll
            for (int s=0;s<2;++s) {
                int blk = tid + s*256;
                int r = blk >> 2, kb = blk & 3;
                *(short8*)&As[r*32 + kb*8] = load8_f32_bf16(&A[(size_t)(m0+r)*TOKDIM + k0 + kb*8]);
            }
        }
        #pragma unroll
        for (int j=0;j<2;++j) {
            const int rb = (wave*2 + j) * 16;
            stage16(&Wq[(size_t)(n0 + rb + srow)*TOKDIM + k0 + scol], &Bs[rb*32]);
        }
        __syncthreads();

        short8 af[4], bfr[4];
        #pragma unroll
        for (int i=0;i<4;i++) af[i]  = *(const short8*)&As[(wm*64 + i*16 + col16)*32 + quad*8];
        #pragma unroll
        for (int j=0;j<4;j++) bfr[j] = *(const short8*)&Bs[(wn*64 + j*16 + col16)*32 + quad*8];
        #pragma unroll
        for (int i=0;i<4;i++)
            #pragma unroll
            for (int j=0;j<4;j++)
                acc[i][j] = __builtin_amdgcn_mfma_f32_16x16x32_bf16(af[i], bfr[j], acc[i][j], 0,0,0);
    }

    #pragma unroll
    for (int i=0;i<4;i++)
        #pragma unroll
        for (int j=0;j<4;j++) {
            const int n = n0 + wn*64 + j*16 + col16;
            const int part = n >> 10;         // 0=Q 1=K 2=V
            const int h = (n & 1023) >> 6;
            const int d = n & 63;
            const int mb = m0 + wm*64 + i*16 + quad*4;
            const int b = mb >> 11;
            const int t = mb & 2047;
            if (part == 2) {
                union { short4v s; int2 i2; } w;
                #pragma unroll
                for (int r=0;r<4;r++) w.s[r] = f2b(acc[i][j][r]);
                *(int2*)&Vto[((size_t)(b*HEADS + h)*HDIM + d)*SEQ + t] = w.i2;
            } else {
                short* dst = (part == 0) ? Qo : Ko;
                #pragma unroll
                for (int r=0;r<4;r++)
                    dst[((size_t)(b*HEADS + h)*SEQ + t + r)*HDIM + d] = f2b(acc[i][j][r]);
            }
        }
}

// ---------------------------------------------------------------------------
// Out GEMM v2 (round-12 verified, DEFAULT dispatch — round-16's swizzle was
// part of the +8.5us regression; revert). 64x128 tile, grid 512, BK=64,
// dbuf swizzled stage16, issue-early, one vmcnt(0)+barrier per K-tile.
// ---------------------------------------------------------------------------
#define OBM 64
#define OBN 128
#define OBK 64
#define OKT (TOKDIM/OBK)   // 16 K-tiles

__global__ __launch_bounds__(256)
void gemm_out(const short* __restrict__ A, const short* __restrict__ W,
              const float* __restrict__ bias, float* __restrict__ C)
{
    __shared__ __align__(16) short Asl[2*OBM*OBK];   // 16 KB
    __shared__ __align__(16) short Bsl[2*OBN*OBK];   // 32 KB
    const int tid  = threadIdx.x;
    const int lane = tid & 63;
    const int wave = tid >> 6;
    const int wm = wave >> 1, wn = wave & 1;
    const int m0 = blockIdx.x * OBM;
    const int n0 = blockIdx.y * OBN;
    const int col16 = lane & 15, quad = lane >> 4;

    // staging: each stage16 covers 8 rows x 128B; lane -> row lane>>3,
    // physical chunk lane&7 holds logical chunk (lane&7)^(row&7).
    const int srow = lane >> 3;                      // 0..7
    const int scol = (((lane & 7) ^ srow) << 3);     // source col, shorts

    // read-side: logical chunk (kk*4+quad) -> physical ^ (row&7)
    const int r7 = col16 & 7;
    const int rdoff0 = ((0*4 + quad) ^ r7) << 3;
    const int rdoff1 = ((1*4 + quad) ^ r7) << 3;

    float4v acc[2][4];
    #pragma unroll
    for (int i=0;i<2;i++)
        #pragma unroll
        for (int j=0;j<4;j++) acc[i][j] = (float4v){0.f,0.f,0.f,0.f};

    // ---- prologue: stage K-tile 0 into buffer 0 ----
    #pragma unroll
    for (int c=0;c<2;++c) {
        const int rb = (wave*2 + c)*8;               // 8 groups = 64 A rows
        stage16(&A[(size_t)(m0 + rb + srow)*TOKDIM + scol], &Asl[rb*OBK]);
    }
    #pragma unroll
    for (int c=0;c<4;++c) {
        const int rb = (wave*4 + c)*8;               // 16 groups = 128 W rows
        stage16(&W[(size_t)(n0 + rb + srow)*TOKDIM + scol], &Bsl[rb*OBK]);
    }
    asm volatile("s_waitcnt vmcnt(0)" ::: "memory");
    __builtin_amdgcn_s_barrier();

    for (int kt = 0; kt < OKT; ++kt) {
        const int buf = kt & 1;
        const short* Ab = &Asl[buf*OBM*OBK];
        const short* Bb = &Bsl[buf*OBN*OBK];
        short* An = &Asl[(buf^1)*OBM*OBK];
        short* Bn = &Bsl[(buf^1)*OBN*OBK];

        // issue next K-tile's stages FIRST (latency hides under compute)
        if (kt + 1 < OKT) {
            const int k1 = (kt + 1)*OBK;
            #pragma unroll
            for (int c=0;c<2;++c) {
                const int rb = (wave*2 + c)*8;
                stage16(&A[(size_t)(m0 + rb + srow)*TOKDIM + k1 + scol], &An[rb*OBK]);
            }
            #pragma unroll
            for (int c=0;c<4;++c) {
                const int rb = (wave*4 + c)*8;
                stage16(&W[(size_t)(n0 + rb + srow)*TOKDIM + k1 + scol], &Bn[rb*OBK]);
            }
        }

        #pragma unroll
        for (int kk=0;kk<2;++kk) {
            const int rdoff = kk ? rdoff1 : rdoff0;
            short8 af[2], bfr[4];
            #pragma unroll
            for (int i=0;i<2;i++)
                af[i]  = *(const short8*)&Ab[(wm*32 + i*16 + col16)*OBK + rdoff];
            #pragma unroll
            for (int j=0;j<4;j++)
                bfr[j] = *(const short8*)&Bb[(wn*64 + j*16 + col16)*OBK + rdoff];
            __builtin_amdgcn_s_setprio(1);
            #pragma unroll
            for (int i=0;i<2;i++)
                #pragma unroll
                for (int j=0;j<4;j++)
                    acc[i][j] = __builtin_amdgcn_mfma_f32_16x16x32_bf16(af[i], bfr[j], acc[i][j], 0,0,0);
            __builtin_amdgcn_s_setprio(0);
        }

        // own kt+1 loads done; barrier aligns all waves and gates buf^1 reuse
        asm volatile("s_waitcnt vmcnt(0)" ::: "memory");
        __builtin_amdgcn_s_barrier();
    }

    #pragma unroll
    for (int i=0;i<2;i++)
        #pragma unroll
        for (int j=0;j<4;j++) {
            const int n = n0 + wn*64 + j*16 + col16;
            const float bn = bias[n];
            #pragma unroll
            for (int r=0;r<4;r++) {
                const int m = m0 + wm*32 + i*16 + quad*4 + r;
                C[(size_t)m*TOKDIM + n] = acc[i][j][r] + bn;
            }
        }
}

// ---------------------------------------------------------------------------
// Flash attention v13 (round-15 verified best: XCD swizzle cut FETCH
// 69.7->12.4 MB; 0 bank conflicts; ~45 us = structural floor after 5 failed
// restructure attempts). v10 DMA-swizzle structure + ones-MFMA lsum +
// setprio + XCD-chunked grid swizzle. Do not restructure.
// ---------------------------------------------------------------------------
#define AQB 128
#define KT  64
#define NTH 16             // tiles per key-half
#define KVT (KT*HDIM)      // 4096 shorts per K or V tile
#define BUF2 (2*KVT)       // 8192 shorts per buffer (K|V)

__global__ __launch_bounds__(256, 2)
void attn_kernel(const short* __restrict__ Q, const short* __restrict__ K,
                 const short* __restrict__ Vt, short* __restrict__ AO)
{
    // layout: [stream 0..1][buf 0..1][ K(64x64) | V(64x64) ]  = 65536 B
    __shared__ __align__(16) short SL[2*2*BUF2];

    const int tid   = threadIdx.x;
    const int lane  = tid & 63;
    const int wave  = tid >> 6;
    const int col16 = lane & 15, quad = lane >> 4;

    // ---- XCD-chunked bijective swizzle (grid 16 x 32 = 512, %8==0) ----
    const int lin  = blockIdx.x + gridDim.x * blockIdx.y;
    const int wgid = (lin & 7) * 64 + (lin >> 3);
    const int bx   = wgid & 15;                // gridDim.x == 16
    const int bh   = wgid >> 4;

    const int qh  = wave & 1;
    const int kh2 = wave >> 1;                 // key half == stream
    const int qb  = bx*AQB + qh*64;

    const short* Qb = Q  + (size_t)bh*SEQ*HDIM;
    const short* Kb = K  + (size_t)bh*SEQ*HDIM;
    const short* Vb = Vt + (size_t)bh*HDIM*SEQ;

    short* Sbase = &SL[kh2*2*BUF2];            // this stream's two buffers
    const int kbase = kh2 * 1024;              // first key of this stream

    // ---- staging constants ----
    const int w   = wave & 1;
    const int l3  = lane >> 3;
    const int scsw = (((lane & 7) ^ l3) << 4) >> 1;   // swizzled col, shorts
    int krow[4], vrow[4];
    #pragma unroll
    for (int c=0;c<4;++c) {
        const int s = w*32 + c*8 + l3;         // dest slot / V d-row
        krow[c] = (s&32) + ((s&12)<<1) + ((s&16)>>2) + (s&3);   // ksinv(s)
        vrow[c] = s;
    }

    // ---- read-side swizzled column offsets (shorts) ----
    const int r7 = col16 & 7;
    int scol2[2];
    #pragma unroll
    for (int j=0;j<2;++j)
        scol2[j] = ((((j<<6) | (quad<<4)) ^ (r7<<4)) >> 1);

    // Q B-frags for 4 q-groups, pre-scaled by 0.125*log2(e)
    const float qscale = 0.125f * 1.44269504088896f;
    short8 qf[4][2];
    #pragma unroll
    for (int qg=0; qg<4; ++qg)
        #pragma unroll
        for (int kk=0; kk<2; ++kk) {
            short8 raw = *(const short8*)&Qb[(size_t)(qb+qg*16+col16)*HDIM + kk*32 + quad*8];
            #pragma unroll
            for (int j=0;j<8;++j) raw[j] = f2b(b2f(raw[j]) * qscale);
            qf[qg][kk] = raw;
        }

    // all-ones bf16 A-fragment for the lsum MFMA
    const short one_bf16 = (short)0x3F80;
    const short8 vones = {one_bf16, one_bf16, one_bf16, one_bf16,
                          one_bf16, one_bf16, one_bf16, one_bf16};

    float4v o[4][4];
    float4v o1[4];
    #pragma unroll
    for (int qg=0;qg<4;qg++) {
        #pragma unroll
        for (int dt=0;dt<4;dt++) o[qg][dt] = (float4v){0.f,0.f,0.f,0.f};
        o1[qg] = (float4v){0.f,0.f,0.f,0.f};
    }

    // ---- stage tile 0 into buffer 0 (async DMA) ----
    {
        short* Kn = Sbase;
        short* Vn = Sbase + KVT;
        #pragma unroll
        for (int c=0;c<4;++c) {
            stage16(&Kb[(size_t)(kbase + krow[c])*HDIM + scsw], &Kn[w*2048 + c*512]);
            stage16(&Vb[(size_t)vrow[c]*SEQ + kbase + scsw],    &Vn[w*2048 + c*512]);
        }
    }
    __syncthreads();                           // vmcnt(0) drain + barrier

    for (int t = 0; t < NTH; ++t) {
        short* Kc = Sbase + (t & 1)*BUF2;
        short* Vc = Kc + KVT;

        // issue next tile's async stages FIRST (latency hides under compute)
        if (t + 1 < NTH) {
            const int g1 = kbase + (t+1)*KT;
            short* Kn = Sbase + ((t & 1)^1)*BUF2;
            short* Vn = Kn + KVT;
            #pragma unroll
            for (int c=0;c<4;++c) {
                stage16(&Kb[(size_t)(g1 + krow[c])*HDIM + scsw], &Kn[w*2048 + c*512]);
                stage16(&Vb[(size_t)vrow[c]*SEQ + g1 + scsw],    &Vn[w*2048 + c*512]);
            }
        }

        // ---- compute on buffer (t&1) of this stream ----
        #pragma unroll
        for (int kk = 0; kk < 2; ++kk) {
            short8 ka[2][2];
            #pragma unroll
            for (int nt=0; nt<2; ++nt)
                #pragma unroll
                for (int kh=0; kh<2; ++kh)
                    ka[nt][kh] = *(const short8*)&Kc[(kk*32 + nt*16 + col16)*64 + scol2[kh]];
            short8 va[4];
            #pragma unroll
            for (int dt=0; dt<4; ++dt)
                va[dt] = *(const short8*)&Vc[(dt*16 + col16)*64 + scol2[kk]];

            #pragma unroll
            for (int qg=0; qg<4; ++qg) {
                float4v st[2];
                __builtin_amdgcn_s_setprio(1);
                #pragma unroll
                for (int nt=0; nt<2; ++nt) {
                    float4v z = (float4v){0.f,0.f,0.f,0.f};
                    z = __builtin_amdgcn_mfma_f32_16x16x32_bf16(ka[nt][0], qf[qg][0], z, 0,0,0);
                    z = __builtin_amdgcn_mfma_f32_16x16x32_bf16(ka[nt][1], qf[qg][1], z, 0,0,0);
                    st[nt] = z;
                }
                __builtin_amdgcn_s_setprio(0);
                union { int i[4]; short8 s8; } pb;
                float p00 = hexp2(st[0][0]), p01 = hexp2(st[0][1]);
                float p02 = hexp2(st[0][2]), p03 = hexp2(st[0][3]);
                float p10 = hexp2(st[1][0]), p11 = hexp2(st[1][1]);
                float p12 = hexp2(st[1][2]), p13 = hexp2(st[1][3]);
                pb.i[0] = packrn(p00, p01); pb.i[1] = packrn(p02, p03);
                pb.i[2] = packrn(p10, p11); pb.i[3] = packrn(p12, p13);

                __builtin_amdgcn_s_setprio(1);
                #pragma unroll
                for (int dt=0; dt<4; ++dt)
                    o[qg][dt] = __builtin_amdgcn_mfma_f32_16x16x32_bf16(va[dt], pb.s8, o[qg][dt], 0,0,0);
                // row-sum of the same packed P: D[i][j] = sum_k P[k][j]
                o1[qg] = __builtin_amdgcn_mfma_f32_16x16x32_bf16(vones, pb.s8, o1[qg], 0,0,0);
                __builtin_amdgcn_s_setprio(0);
            }
        }

        __syncthreads();        // drains vmcnt (stages complete) + orders reads
    }

    // lsum: every lane of o1 holds the full key-half row sum for q = qg*16+col16
    float lsum[4];
    #pragma unroll
    for (int qg=0; qg<4; ++qg) lsum[qg] = o1[qg][0];

    // ---- merge key-halves through LDS (region: 2 qh x 64 lanes x 68 floats) ----
    float* M = (float*)SL;
    float* Mw = M + (qh*64 + lane)*68;
    if (kh2 == 1) {
        #pragma unroll
        for (int qg=0; qg<4; ++qg) {
            #pragma unroll
            for (int dt=0; dt<4; ++dt)
                *(float4v*)&Mw[(qg*4+dt)*4] = o[qg][dt];
            Mw[64+qg] = lsum[qg];
        }
    }
    __syncthreads();
    if (kh2 == 0) {
        const int b = bh >> 4, h = bh & 15;
        #pragma unroll
        for (int qg=0; qg<4; ++qg) {
            lsum[qg] += Mw[64+qg];
            const float inv = 1.0f / lsum[qg];
            const int tq = qb + qg*16 + col16;
            #pragma unroll
            for (int dt=0; dt<4; ++dt) {
                float4v ov = o[qg][dt] + *(const float4v*)&Mw[(qg*4+dt)*4];
                union { short4v s; int2 i2; } w2;
                #pragma unroll
                for (int r=0;r<4;++r) w2.s[r] = f2b(ov[r] * inv);
                *(int2*)&AO[((size_t)(b*SEQ + tq))*TOKDIM + h*64 + dt*16 + quad*4] = w2.i2;
            }
        }
    }
}

// ---------------------------------------------------------------------------
extern "C" void kernel_launch(void* const* d_in, const int* in_sizes, int n_in,
                              void* d_out, int out_size, void* d_ws, size_t ws_size,
                              hipStream_t stream)
{
    const float* x    = (const float*)d_in[0];   // [2,2048,1024] fp32
    const float* wqkv = (const float*)d_in[1];   // [3072,1024]   fp32
    const float* wout = (const float*)d_in[2];   // [1024,1024]   fp32
    const float* bout = (const float*)d_in[3];   // [1024]        fp32
    float* out = (float*)d_out;                  // [2,2048,1024] fp32

    char* ws = (char*)d_ws;
    const size_t SZ   = (size_t)BH*SEQ*HDIM*sizeof(short);     // 8 MiB
    const size_t WQB  = (size_t)3*TOKDIM*TOKDIM*sizeof(short); // 6 MiB
    const size_t WOB  = (size_t)TOKDIM*TOKDIM*sizeof(short);   // 2 MiB
    const size_t NEED_FULL = SZ + WQB + WOB + 3*SZ;            // 40 MiB
    const bool full = ws_size >= NEED_FULL;

    short *Xb, *Wqb, *Wob, *Qt, *Kt, *Vt, *AO;
    if (full) {
        Xb  = (short*)ws;
        Wqb = (short*)(ws + SZ);
        Wob = (short*)(ws + SZ + WQB);
        Qt  = (short*)(ws + SZ + WQB + WOB);
        Kt  = Qt + SZ/2;
        Vt  = Kt + SZ/2;
        AO  = Xb;
    } else {
        Xb  = nullptr;
        Wqb = (short*)ws;
        Wob = (short*)(ws + WQB);
        Qt  = (short*)(ws + WQB + WOB);
        Kt  = Qt + SZ/2;
        Vt  = Kt + SZ/2;
        AO  = Vt + SZ/2;
    }

    const int n8x = full ? (BATCH*SEQ*TOKDIM)/8 : 0;
    const int n8q = (3*TOKDIM*TOKDIM)/8;
    const int n8o = (TOKDIM*TOKDIM)/8;
    const int cvt_blocks = (n8x + n8q + n8o + 255) / 256;
    cvt_bf16<<<cvt_blocks, 256, 0, stream>>>(x, Xb, n8x, wqkv, Wqb, n8q, wout, Wob, n8o);

    if (full)
        gemm_qkv<1><<<dim3(MROWS/128, (3*TOKDIM)/128), 256, 0, stream>>>(
            (const void*)Xb, Wqb, Qt, Kt, Vt);
    else
        gemm_qkv<0><<<dim3(MROWS/128, (3*TOKDIM)/128), 256, 0, stream>>>(
            (const void*)x, Wqb, Qt, Kt, Vt);

    attn_kernel<<<dim3(SEQ/AQB, BH), 256, 0, stream>>>(Qt, Kt, Vt, AO);

    gemm_out<<<dim3(MROWS/OBM, TOKDIM/OBN), 256, 0, stream>>>(AO, Wob, bout, out);
}